// Round 8
// baseline (941.748 us; speedup 1.0000x reference)
//
#include <hip/hip_runtime.h>
#include <stdint.h>
#include <math.h>

#define R_ 16
#define C_ 256
#define B_ 12
#define E_ 768
#define H_ 12
#define D_ 64
#define TOK (R_*C_*B_)          // 49152
#define HALF_TOK 24576

#define QK_HALF 37748736       // shorts per q or k buffer (49152*768)
#define VT_BASE 37748736       // shorts: vt_all @ d_out byte 75,497,472
#define VT_QUARTER 9437184     // shorts per r-quarter (144*256*256)
#define CTXQ_ELEMS 9437184     // shorts per ctx quarter (12288*768)

typedef __bf16 bf16x8 __attribute__((ext_vector_type(8)));
typedef float floatx4 __attribute__((ext_vector_type(4)));

__device__ __forceinline__ unsigned short f2bf(float f) {
    union { unsigned int i; float f; } v; v.f = f;
    unsigned int i = v.i;
    return (unsigned short)((i + 0x7fffu + ((i >> 16) & 1u)) >> 16);  // RNE
}
__device__ __forceinline__ bf16x8 cvt8(floatx4 lo, floatx4 hi) {
    bf16x8 r;
    r[0] = (__bf16)lo[0]; r[1] = (__bf16)lo[1]; r[2] = (__bf16)lo[2]; r[3] = (__bf16)lo[3];
    r[4] = (__bf16)hi[0]; r[5] = (__bf16)hi[1]; r[6] = (__bf16)hi[2]; r[7] = (__bf16)hi[3];
    return r;
}
__device__ __forceinline__ void gload16(const unsigned short* g, unsigned short* l) {
    __builtin_amdgcn_global_load_lds(
        (const __attribute__((address_space(1))) unsigned int*)g,
        (__attribute__((address_space(3))) unsigned int*)l, 16, 0, 0);
}

// ---------------------------------------------------------------------------
// 128x128 A*B^T GEMM body. B always bf16 via global_load_lds(16B).
// A via global_load_lds for MODE 0/3/4 (bf16 src); f32-load+cvt+ds_write for
// MODE 2 (probs). LDS k-chunk XOR swizzle on global SOURCE addr (kko),
// inverse on frag read. XCD swizzle: same (lin%8) => same XCD.
//
// MODE 0: q+k proj, HALF of tokens. A = x_bf bf16 [24576][768] (half nBase);
//         Bt = wqk_bf [1536][768]; grid (12,192).
//         out bf16 q_s/k_s[((n*12+h)*256+i)*1024 + r*64+d] (global token).
// MODE 2: PV quarter (nBase=q). z: h=bz%12, n=bz/12. A = probs f32 (cvt),
//         K=256(j); B = vt[VT_BASE + q*VT_QUARTER + ((n*12+h)*256+row)*256+j]
//         AGL. grid (2,2,144). out ctx_q[(((cc>>6)*256+i)*12+n)*768+h*64+d].
// MODE 3: V-proj ALL n. A = x_bf bf16 [49152][768] AGL; Bt = wv_bf.
//         grid (6,384). out vt (r-quartered, see above) + bv.
// MODE 4: O quarter (nBase=q). A = ctx_q bf16 AGL [12288][768]; Bt = wo_bf.
//         grid (6,96). f32 out rows q*12288+rowg (token-contiguous) + bo.
// ---------------------------------------------------------------------------
template<int MODE>
__global__ __launch_bounds__(256)
void gemm_bt(const void* __restrict__ Ap,
             const void* __restrict__ Btp,
             const float* __restrict__ bias,
             void* __restrict__ Cout,
             int nBase)
{
    __shared__ __align__(16) unsigned short As[128 * 32];
    __shared__ __align__(16) unsigned short Bs[128 * 32];

    constexpr bool AGL = (MODE != 2);
    constexpr int K = (MODE == 2) ? 256 : 768;
    constexpr int kIters = K >> 5;
    constexpr int GX = (MODE==0) ? 12 : (MODE==2) ? 2 : (MODE==3) ? 6 : 6;
    constexpr int GY = (MODE==0) ? 192 : (MODE==2) ? 2 : (MODE==3) ? 384 : 96;
    constexpr int GZ = (MODE==2) ? 144 : 1;

    const int tid  = threadIdx.x;
    const int wave = tid >> 6, lane = tid & 63;
    const int quad = lane >> 4, l15 = lane & 15;
    const int wr = wave >> 1, wc = wave & 1;

    const int lin = ((int)blockIdx.z * GY + (int)blockIdx.y) * GX + (int)blockIdx.x;
    const int tt  = (lin & 7) * ((GX * GY * GZ) >> 3) + (lin >> 3);
    const int bx  = tt % GX;
    const int rem = tt / GX;
    const int by  = rem % GY, bz = rem / GY;
    const int row0 = by * 128, col0 = bx * 128;

    int hIdx = 0, nIdx = 0;
    if (MODE == 2) { hIdx = bz % 12; nIdx = bz / 12; }

    // staging: slot idx = it*256+tid -> row = idx>>2, ck = idx&3.
    // LDS slot (row,ck) holds logical k-chunk (ck ^ sw), sw = (row>>1)&3.
    const int rA0 = tid >> 2;
    const int ck  = tid & 3;
    const int sw  = (tid >> 3) & 3;
    const int kko = ((ck ^ sw) << 3);      // element offset of sourced chunk

    // ---- B row base pointers (bf16, GL) ----
    const unsigned short* Bt = (const unsigned short*)Btp;
    const unsigned short *gB0, *gB1;
    if (MODE == 2) {
        const size_t vq = VT_BASE + (size_t)nBase * VT_QUARTER
                          + ((size_t)(nIdx * 12 + hIdx) * 256) * 256;
        gB0 = Bt + vq + (size_t)(col0 + rA0) * 256 + kko;
        gB1 = Bt + vq + (size_t)(col0 + rA0 + 64) * 256 + kko;
    } else {
        gB0 = Bt + (size_t)(col0 + rA0) * 768 + kko;
        gB1 = Bt + (size_t)(col0 + rA0 + 64) * 768 + kko;
    }

    // ---- A row base pointers ----
    const unsigned short* gA0u = nullptr; const unsigned short* gA1u = nullptr;
    const float* gA0f = nullptr; const float* gA1f = nullptr;
    if (AGL) {   // MODE 0/3/4: bf16 rows of width 768
        gA0u = (const unsigned short*)Ap + (size_t)(row0 + rA0) * 768 + kko;
        gA1u = (const unsigned short*)Ap + (size_t)(row0 + rA0 + 64) * 768 + kko;
    } else {     // MODE 2: probs f32
        gA0f = (const float*)Ap + ((size_t)(hIdx * 12 + nIdx)) * 65536
               + (size_t)(row0 + rA0) * 256 + kko;
        gA1f = (const float*)Ap + ((size_t)(hIdx * 12 + nIdx)) * 65536
               + (size_t)(row0 + rA0 + 64) * 256 + kko;
    }

    // wave-uniform LDS bases for gload_lds (lane deposits at base + lane*16B)
    unsigned short* lA0 = As + wave * 512;
    unsigned short* lA1 = As + 2048 + wave * 512;
    unsigned short* lB0 = Bs + wave * 512;
    unsigned short* lB1 = Bs + 2048 + wave * 512;

    const floatx4 zero = {0.f, 0.f, 0.f, 0.f};
    floatx4 acc[4][4];
#pragma unroll
    for (int i = 0; i < 4; ++i)
#pragma unroll
        for (int j = 0; j < 4; ++j) acc[i][j] = zero;

    // fragment read swizzle: chunk = quad ^ ((l15>>1)&3)
    const int chO = ((quad ^ ((l15 >> 1) & 3)) << 3);   // shorts

    floatx4 u0l = zero, u0h = zero, u1l = zero, u1h = zero;
    floatx4 p0l = zero, p0h = zero, p1l = zero, p1h = zero;
    if (!AGL) {
        u0l = *(const floatx4*)(gA0f);     u0h = *(const floatx4*)(gA0f + 4);
        u1l = *(const floatx4*)(gA1f);     u1h = *(const floatx4*)(gA1f + 4);
    }

#define GSTEP(KT, UL0, UH0, UL1, UH1, PL0, PH0, PL1, PH1)                         \
    {                                                                              \
        __syncthreads();  /* prev LDS readers done */                              \
        gload16(gB0 + (KT) * 32, lB0);                                             \
        gload16(gB1 + (KT) * 32, lB1);                                             \
        if (AGL) {                                                                 \
            gload16(gA0u + (KT) * 32, lA0);                                        \
            gload16(gA1u + (KT) * 32, lA1);                                        \
        } else {                                                                   \
            *(bf16x8*)(As + tid * 8)        = cvt8(UL0, UH0);                      \
            *(bf16x8*)(As + 2048 + tid * 8) = cvt8(UL1, UH1);                      \
        }                                                                          \
        __syncthreads();  /* LDS tiles valid */                                    \
        if (!AGL && ((KT) + 1 < kIters)) {  /* prefetch overlaps MFMA */           \
            PL0 = *(const floatx4*)(gA0f + ((KT) + 1) * 32);                       \
            PH0 = *(const floatx4*)(gA0f + ((KT) + 1) * 32 + 4);                   \
            PL1 = *(const floatx4*)(gA1f + ((KT) + 1) * 32);                       \
            PH1 = *(const floatx4*)(gA1f + ((KT) + 1) * 32 + 4);                   \
        }                                                                          \
        bf16x8 af[4], bfr[4];                                                      \
        _Pragma("unroll")                                                          \
        for (int t = 0; t < 4; ++t) {                                              \
            af[t]  = *(const bf16x8*)(As + (wr * 64 + t * 16 + l15) * 32 + chO);   \
            bfr[t] = *(const bf16x8*)(Bs + (wc * 64 + t * 16 + l15) * 32 + chO);   \
        }                                                                          \
        _Pragma("unroll")                                                          \
        for (int tm = 0; tm < 4; ++tm)                                             \
            _Pragma("unroll")                                                      \
            for (int tn = 0; tn < 4; ++tn)                                         \
                acc[tm][tn] = __builtin_amdgcn_mfma_f32_16x16x32_bf16(             \
                    af[tm], bfr[tn], acc[tm][tn], 0, 0, 0);                        \
    }

    for (int kt = 0; kt < kIters; kt += 2) {
        GSTEP(kt,     u0l, u0h, u1l, u1h, p0l, p0h, p1l, p1h);
        GSTEP(kt + 1, p0l, p0h, p1l, p1h, u0l, u0h, u1l, u1h);
    }
#undef GSTEP

    // Epilogue. C/D layout: col = lane&15, row = quad*4 + reg.
#pragma unroll
    for (int tm = 0; tm < 4; ++tm) {
        const int rbase = row0 + wr * 64 + tm * 16 + quad * 4;
#pragma unroll
        for (int tn = 0; tn < 4; ++tn) {
            const int cc = col0 + wc * 64 + tn * 16 + l15;
#pragma unroll
            for (int rr = 0; rr < 4; ++rr) {
                float vv = acc[tm][tn][rr];
                const int rowg = rbase + rr;
                if (MODE == 0) {     // q_s/k_s[((n*12+h)*256+i)*1024 + r*64+d]
                    const int tg = nBase * HALF_TOK + rowg;   // global token
                    const int m = tg / 12, n = tg - m * 12;
                    const int r = m >> 8, i = m & 255;
                    const int sel = cc >= 768 ? 1 : 0;
                    const int ccl = cc - sel * 768;
                    const int h = ccl >> 6, d = ccl & 63;
                    ((unsigned short*)Cout)[(size_t)sel * QK_HALF
                        + ((size_t)(n * 12 + h) * 256 + i) * 1024 + r * 64 + d]
                        = f2bf(vv + bias[cc]);
                } else if (MODE == 2) {   // ctx_q[(((cc>>6)*256+i)*12+n)*768 + h*64+d]
                    ((unsigned short*)Cout)[((((size_t)(cc >> 6)) * 256 + rowg) * 12
                        + nIdx) * 768 + hIdx * 64 + (cc & 63)] = f2bf(vv);
                } else if (MODE == 3) {   // vt quarter scatter; rowg = token
                    const int m = rowg / 12, n = rowg - m * 12;
                    const int r = m >> 8, j = m & 255;
                    const int h = cc >> 6, d = cc & 63;
                    ((unsigned short*)Cout)[VT_BASE + (size_t)(r >> 2) * VT_QUARTER
                        + ((size_t)(n * 12 + h) * 256 + (r & 3) * 64 + d) * 256 + j]
                        = f2bf(vv + bias[cc]);
                } else {                  // MODE 4: f32 out token-contiguous
                    ((float*)Cout)[((size_t)(nBase * 12288 + rowg)) * 768 + cc]
                        = vv + bias[cc];
                }
            }
        }
    }
}

// ---------------------------------------------------------------------------
// Fused scores + bias + softmax. Tile 128 rows x 256 cols (full softmax rows
// in-block). 512 threads = 8 waves; wave w owns rows [w*16,w*16+16), acc[16].
// Both operands AGL, K=1024. grid (1,2,144); z = n*12+h pair-block layout.
// ---------------------------------------------------------------------------
__global__ __launch_bounds__(512)
void scores_sm(const unsigned short* __restrict__ q,
               const unsigned short* __restrict__ k,
               const int* __restrict__ buckets,
               const float* __restrict__ rb,
               float* __restrict__ probs)
{
    __shared__ __align__(16) unsigned short As[128 * 32];   //  8 KB
    __shared__ __align__(16) unsigned short Bs[256 * 32];   // 16 KB

    const int tid  = threadIdx.x;
    const int w    = tid >> 6, lane = tid & 63;
    const int quad = lane >> 4, l15 = lane & 15;

    const int lin = (int)blockIdx.z * 2 + (int)blockIdx.y;
    const int tt  = (lin & 7) * 36 + (lin >> 3);
    const int by  = tt % 2, bz = tt / 2;
    const int row0 = by * 128;
    const int h = bz % 12, n = bz / 12;

    const int rA0 = tid >> 2;
    const int ck  = tid & 3;
    const int sw  = (tid >> 3) & 3;
    const int kko = ((ck ^ sw) << 3);

    const unsigned short* gA  = q + ((size_t)bz * 256 + row0 + rA0) * 1024 + kko;
    const unsigned short* gB0 = k + ((size_t)bz * 256 + rA0) * 1024 + kko;
    const unsigned short* gB1 = k + ((size_t)bz * 256 + rA0 + 128) * 1024 + kko;

    unsigned short* lA  = As + w * 512;
    unsigned short* lB0 = Bs + w * 512;
    unsigned short* lB1 = Bs + 4096 + w * 512;

    const floatx4 zero = {0.f, 0.f, 0.f, 0.f};
    floatx4 acc[16];
#pragma unroll
    for (int t = 0; t < 16; ++t) acc[t] = zero;

    const int chO = ((quad ^ ((l15 >> 1) & 3)) << 3);

    for (int kt = 0; kt < 32; ++kt) {
        __syncthreads();
        gload16(gA  + kt * 32, lA);
        gload16(gB0 + kt * 32, lB0);
        gload16(gB1 + kt * 32, lB1);
        __syncthreads();
        const bf16x8 af = *(const bf16x8*)(As + (w * 16 + l15) * 32 + chO);
#pragma unroll
        for (int tn = 0; tn < 16; ++tn) {
            const bf16x8 bfr = *(const bf16x8*)(Bs + (tn * 16 + l15) * 32 + chO);
            acc[tn] = __builtin_amdgcn_mfma_f32_16x16x32_bf16(af, bfr, acc[tn], 0, 0, 0);
        }
    }

    const int i0 = row0 + w * 16 + quad * 4;
    float mx[4] = {-3.4e38f, -3.4e38f, -3.4e38f, -3.4e38f};
#pragma unroll
    for (int tn = 0; tn < 16; ++tn) {
        const int j = tn * 16 + l15;
#pragma unroll
        for (int rr = 0; rr < 4; ++rr) {
            const int bkt = buckets[((size_t)h * 256 + i0 + rr) * 256 + j];
            const float s = acc[tn][rr] * 0.03125f + rb[bkt * 12 + n];
            acc[tn][rr] = s;
            mx[rr] = fmaxf(mx[rr], s);
        }
    }
#pragma unroll
    for (int rr = 0; rr < 4; ++rr)
#pragma unroll
        for (int off = 1; off < 16; off <<= 1)
            mx[rr] = fmaxf(mx[rr], __shfl_xor(mx[rr], off, 64));
    float sm[4] = {0.f, 0.f, 0.f, 0.f};
#pragma unroll
    for (int tn = 0; tn < 16; ++tn)
#pragma unroll
        for (int rr = 0; rr < 4; ++rr) {
            const float e = expf(acc[tn][rr] - mx[rr]);
            acc[tn][rr] = e;
            sm[rr] += e;
        }
#pragma unroll
    for (int rr = 0; rr < 4; ++rr)
#pragma unroll
        for (int off = 1; off < 16; off <<= 1)
            sm[rr] += __shfl_xor(sm[rr], off, 64);
    float inv[4];
#pragma unroll
    for (int rr = 0; rr < 4; ++rr) inv[rr] = 1.f / sm[rr];

    float* prow = probs + ((size_t)(h * 12 + n)) * 65536;
#pragma unroll
    for (int tn = 0; tn < 16; ++tn) {
        const int j = tn * 16 + l15;
#pragma unroll
        for (int rr = 0; rr < 4; ++rr)
            prow[(size_t)(i0 + rr) * 256 + j] = acc[tn][rr] * inv[rr];
    }
}

// ---------------------------------------------------------------------------
// f32 -> bf16 bulk convert, 8 elems/thread. n multiple of 2048.
// ---------------------------------------------------------------------------
__global__ __launch_bounds__(256)
void cvt_bulk(const float* __restrict__ src, unsigned short* __restrict__ dst, int n)
{
    const int i = (blockIdx.x * 256 + threadIdx.x) * 8;
    if (i >= n) return;
    floatx4 a = ((const floatx4*)(src + i))[0];
    floatx4 b = ((const floatx4*)(src + i))[1];
    *(bf16x8*)(dst + i) = cvt8(a, b);
}

// ---------------------------------------------------------------------------
// prep: buckets (blocks 0..3071) + weight cvt & bias concat (blocks 3072..).
// ---------------------------------------------------------------------------
__global__ __launch_bounds__(256)
void prep(const int* __restrict__ dist, int* __restrict__ buckets,
          const float* __restrict__ Wq, const float* __restrict__ Wk,
          const float* __restrict__ Wv, const float* __restrict__ Wo,
          const float* __restrict__ bq, const float* __restrict__ bk,
          unsigned short* __restrict__ wqk, unsigned short* __restrict__ wvb,
          unsigned short* __restrict__ wob, float* __restrict__ bqk)
{
    if (blockIdx.x < 3072) {
        const int idx = blockIdx.x * 256 + threadIdx.x;
        if (idx >= B_ * C_ * C_) return;
        const int dv = dist[idx];
        const int n = dv < 0 ? -dv : dv;
        int bkt;
        if (n < 16) {
            bkt = n;
        } else {
            const float lg = logf((float)n * 0.0625f);        // log(n/16)
            const float t  = (lg / 8.047189562170502f) * 15.0f;
            bkt = 16 + (int)t;
            if (bkt > 31) bkt = 31;
        }
        buckets[idx] = bkt;
        return;
    }
    const int gid = (blockIdx.x - 3072) * 256 + threadIdx.x;
    const int W8 = 73728;                     // 589824 / 8
    if (gid < 4 * W8) {
        const int sec = gid / W8, off = (gid - sec * W8) * 8;
        const float* src = (sec == 0) ? Wq : (sec == 1) ? Wk : (sec == 2) ? Wv : Wo;
        unsigned short* dst = (sec == 0) ? wqk : (sec == 1) ? (wqk + 589824)
                              : (sec == 2) ? wvb : wob;
        floatx4 a = ((const floatx4*)(src + off))[0];
        floatx4 b = ((const floatx4*)(src + off))[1];
        *(bf16x8*)(dst + off) = cvt8(a, b);
    } else {
        const int b = gid - 4 * W8;
        if (b < 1536) bqk[b] = (b < 768) ? bq[b] : bk[b - 768];
    }
}

// ---------------------------------------------------------------------------
// Memory plan.
// d_out (188,743,680 B):
//   [0 : 150,994,944)  -- phase 1/2: q_s [0:75.5M), k_s [75.5M:151M)  (bf16)
//                      -- phase 3:   x_bf [0:75.5M) then O0/O1 overwrite;
//                                    vt_all [75.5M:151M) in r-quarters q=0..3,
//                                    quarter q at VT_BASE + q*VT_QUARTER;
//                                    O2 overwrites q0/q1, O3 overwrites q2/q3
//                                    (each consumed by PV_q before).
//                      -- final:     out f32 rows token-contiguous.
//   probs f32 [150,994,944 : 188,743,680) -- x_bf halves pre-scores; then
//                                    scores_sm writes final probs (live to end).
// d_ws (28,311,552 B) -- ALL DISJOINT, no lifetime reuse:
//   wo_bf   @ 0           (1,179,648)
//   wv_bf   @ 1,179,648   (1,179,648)
//   bqk f32 @ 2,359,296   (6,144)
//   ctx_q   @ 2,365,440   (18,874,368)   [PV_q writes, O_q reads, ping-pong]
//   buckets @ 21,239,808  (3,145,728)
//   wqk_bf  @ 24,385,536  (2,359,296)    -> ends 26,744,832 <= ws_size
// Phase 3: cvt x full -> x_bf; V-proj ALL n (AGL) -> vt_all;
//          for q=0..3: PV_q -> ctx_q (ws); O_q -> out[q*37.7M:(q+1)*37.7M).
// ---------------------------------------------------------------------------
extern "C" void kernel_launch(void* const* d_in, const int* in_sizes, int n_in,
                              void* d_out, int out_size, void* d_ws, size_t ws_size,
                              hipStream_t stream)
{
    const float* x    = (const float*)d_in[0];
    const int*   dist = (const int*)d_in[1];
    const float* Wq   = (const float*)d_in[2];
    const float* bq   = (const float*)d_in[3];
    const float* Wk   = (const float*)d_in[4];
    const float* bk   = (const float*)d_in[5];
    const float* Wv   = (const float*)d_in[6];
    const float* bv   = (const float*)d_in[7];
    const float* Wo   = (const float*)d_in[8];
    const float* bo   = (const float*)d_in[9];
    const float* rb   = (const float*)d_in[10];

    float* outp  = (float*)d_out;
    float* probs = (float*)d_out + (size_t)TOK * E_;      // f32 elem 37,748,736

    unsigned short* dob  = (unsigned short*)d_out;        // bf16 view of out
    unsigned short* qs   = dob;                           // [n][h][i][rd]
    unsigned short* ks   = dob + QK_HALF;
    unsigned short* x_bf = (unsigned short*)probs;        // x half, pre-scores

    char* ws = (char*)d_ws;
    unsigned short* wo_bf  = (unsigned short*)(ws);
    unsigned short* wv_bf  = (unsigned short*)(ws + 1179648);
    float*          bqk    = (float*)(ws + 2359296);
    unsigned short* ctx_q  = (unsigned short*)(ws + 2365440);
    int*            buckets= (int*)(ws + 21239808);
    unsigned short* wqk_bf = (unsigned short*)(ws + 24385536);

    dim3 blk(256);

    prep<<<dim3(4230), blk, 0, stream>>>(dist, buckets, Wq, Wk, Wv, Wo, bq, bk,
                                         wqk_bf, wv_bf, wo_bf, bqk);

    // Phase 1: per-half {cvt x -> bf16 in probs region, fused q+k proj (AGL)}
    for (int half = 0; half < 2; ++half) {
        cvt_bulk<<<dim3(9216), blk, 0, stream>>>(
            x + (size_t)half * HALF_TOK * 768, x_bf, HALF_TOK * 768);
        gemm_bt<0><<<dim3(12, 192), blk, 0, stream>>>(x_bf, wqk_bf, bqk, qs, half);
    }

    // Phase 2: fused scores + bias + softmax (writes final probs f32)
    scores_sm<<<dim3(1, 2, 144), dim3(512), 0, stream>>>(qs, ks, buckets, rb, probs);

    // Phase 3: cvt full x -> x_bf @ out[0:75.5M); V-proj ALL n -> vt_all;
    //          4x (PV quarter -> ctx_q, O quarter -> out).
    cvt_bulk<<<dim3(18432), blk, 0, stream>>>(x, dob, TOK * E_);
    gemm_bt<3><<<dim3(6, 384), blk, 0, stream>>>(dob, wv_bf, bv, dob, 0);
    for (int q = 0; q < 4; ++q) {
        gemm_bt<2><<<dim3(2, 2, 144), blk, 0, stream>>>(probs, dob, nullptr, ctx_q, q);
        gemm_bt<4><<<dim3(6, 96), blk, 0, stream>>>(ctx_q, wo_bf, bo, outp, q);
    }
}

// Round 10
// 862.002 us; speedup vs baseline: 1.0925x; 1.0925x over previous
//
#include <hip/hip_runtime.h>
#include <stdint.h>
#include <math.h>

#define R_ 16
#define C_ 256
#define B_ 12
#define E_ 768
#define H_ 12
#define D_ 64
#define TOK (R_*C_*B_)          // 49152
#define HALF_TOK 24576

#define QK_HALF 37748736       // shorts per q or k buffer (49152*768)
#define VT_BASE 37748736       // shorts: vt_all @ d_out byte 75,497,472
#define VT_QUARTER 9437184     // shorts per r-quarter (144*256*256)

typedef __bf16 bf16x8 __attribute__((ext_vector_type(8)));
typedef float floatx4 __attribute__((ext_vector_type(4)));

__device__ __forceinline__ unsigned short f2bf(float f) {
    union { unsigned int i; float f; } v; v.f = f;
    unsigned int i = v.i;
    return (unsigned short)((i + 0x7fffu + ((i >> 16) & 1u)) >> 16);  // RNE
}
__device__ __forceinline__ bf16x8 cvt8(floatx4 lo, floatx4 hi) {
    bf16x8 r;
    r[0] = (__bf16)lo[0]; r[1] = (__bf16)lo[1]; r[2] = (__bf16)lo[2]; r[3] = (__bf16)lo[3];
    r[4] = (__bf16)hi[0]; r[5] = (__bf16)hi[1]; r[6] = (__bf16)hi[2]; r[7] = (__bf16)hi[3];
    return r;
}
__device__ __forceinline__ void gload16(const unsigned short* g, unsigned short* l) {
    __builtin_amdgcn_global_load_lds(
        (const __attribute__((address_space(1))) unsigned int*)g,
        (__attribute__((address_space(3))) unsigned int*)l, 16, 0, 0);
}

// ---------------------------------------------------------------------------
// 128x128 A*B^T GEMM body. B always bf16 via global_load_lds(16B).
// A via global_load_lds for MODE 0/3/4 (bf16 src); f32-load+cvt+ds_write for
// MODE 2 (probs). LDS k-chunk XOR swizzle on global SOURCE addr (kko),
// inverse on frag read. XCD swizzle: same (lin%8) => same XCD.
//
// MODE 0: q+k proj, HALF of tokens. A = x_bf bf16 [24576][768] (half nBase);
//         Bt = wqk_bf [1536][768]; grid (12,192).
//         out bf16 q_s/k_s[((n*12+h)*256+i)*1024 + r*64+d] (global token).
// MODE 2: PV quarter (nBase=q). z: h=bz%12, n=bz/12. A = probs f32 (cvt),
//         K=256(j); B = vt[VT_BASE + q*VT_QUARTER + ((n*12+h)*256+row)*256+j]
//         AGL. grid (2,2,144). out ctx_q[(((cc>>6)*256+i)*12+n)*768+h*64+d].
// MODE 3: TRANSPOSED V-proj. A = wv_bf [768][768] AGL (rows = e_out);
//         B = x_n[n] bf16 [4096][768] AGL (rows = m, z = n); grid (32,6,12).
//         out v^T: rowg = e_out = h*64+d, cc = m = r*256+j ->
//         vt[VT_BASE + (r>>2)*VT_QUARTER + ((n*12+h)*256+(r&3)*64+d)*256 + j]
//         (j lane-varying -> 32B-contiguous stores) + bv[rowg].
// MODE 4: O quarter (nBase=q). A = ctx_q bf16 AGL [12288][768]; Bt = wo_bf.
//         grid (6,96). f32 out rows q*12288+rowg (token-contiguous) + bo.
// ---------------------------------------------------------------------------
template<int MODE>
__global__ __launch_bounds__(256)
void gemm_bt(const void* __restrict__ Ap,
             const void* __restrict__ Btp,
             const float* __restrict__ bias,
             void* __restrict__ Cout,
             int nBase)
{
    __shared__ __align__(16) unsigned short As[128 * 32];
    __shared__ __align__(16) unsigned short Bs[128 * 32];

    constexpr bool AGL = (MODE != 2);
    constexpr int K = (MODE == 2) ? 256 : 768;
    constexpr int kIters = K >> 5;
    constexpr int GX = (MODE==0) ? 12 : (MODE==2) ? 2 : (MODE==3) ? 32 : 6;
    constexpr int GY = (MODE==0) ? 192 : (MODE==2) ? 2 : (MODE==3) ? 6 : 96;
    constexpr int GZ = (MODE==2) ? 144 : (MODE==3) ? 12 : 1;

    const int tid  = threadIdx.x;
    const int wave = tid >> 6, lane = tid & 63;
    const int quad = lane >> 4, l15 = lane & 15;
    const int wr = wave >> 1, wc = wave & 1;

    const int lin = ((int)blockIdx.z * GY + (int)blockIdx.y) * GX + (int)blockIdx.x;
    const int tt  = (lin & 7) * ((GX * GY * GZ) >> 3) + (lin >> 3);
    const int bx  = tt % GX;
    const int rem = tt / GX;
    const int by  = rem % GY, bz = rem / GY;
    const int row0 = by * 128, col0 = bx * 128;

    int hIdx = 0, nIdx = 0;
    if (MODE == 2) { hIdx = bz % 12; nIdx = bz / 12; }
    if (MODE == 3) { nIdx = bz; }

    // staging: slot idx = it*256+tid -> row = idx>>2, ck = idx&3.
    // LDS slot (row,ck) holds logical k-chunk (ck ^ sw), sw = (row>>1)&3.
    const int rA0 = tid >> 2;
    const int ck  = tid & 3;
    const int sw  = (tid >> 3) & 3;
    const int kko = ((ck ^ sw) << 3);      // element offset of sourced chunk

    // ---- B row base pointers (bf16, GL) ----
    const unsigned short* Bt = (const unsigned short*)Btp;
    const unsigned short *gB0, *gB1;
    if (MODE == 2) {
        const size_t vq = VT_BASE + (size_t)nBase * VT_QUARTER
                          + ((size_t)(nIdx * 12 + hIdx) * 256) * 256;
        gB0 = Bt + vq + (size_t)(col0 + rA0) * 256 + kko;
        gB1 = Bt + vq + (size_t)(col0 + rA0 + 64) * 256 + kko;
    } else if (MODE == 3) {   // x_n[n] rows (m)
        gB0 = Bt + ((size_t)nIdx * 4096 + col0 + rA0) * 768 + kko;
        gB1 = Bt + ((size_t)nIdx * 4096 + col0 + rA0 + 64) * 768 + kko;
    } else {
        gB0 = Bt + (size_t)(col0 + rA0) * 768 + kko;
        gB1 = Bt + (size_t)(col0 + rA0 + 64) * 768 + kko;
    }

    // ---- A row base pointers ----
    const unsigned short* gA0u = nullptr; const unsigned short* gA1u = nullptr;
    const float* gA0f = nullptr; const float* gA1f = nullptr;
    if (AGL) {   // MODE 0/3/4: bf16 rows of width 768
        gA0u = (const unsigned short*)Ap + (size_t)(row0 + rA0) * 768 + kko;
        gA1u = (const unsigned short*)Ap + (size_t)(row0 + rA0 + 64) * 768 + kko;
    } else {     // MODE 2: probs f32
        gA0f = (const float*)Ap + ((size_t)(hIdx * 12 + nIdx)) * 65536
               + (size_t)(row0 + rA0) * 256 + kko;
        gA1f = (const float*)Ap + ((size_t)(hIdx * 12 + nIdx)) * 65536
               + (size_t)(row0 + rA0 + 64) * 256 + kko;
    }

    // wave-uniform LDS bases for gload_lds (lane deposits at base + lane*16B)
    unsigned short* lA0 = As + wave * 512;
    unsigned short* lA1 = As + 2048 + wave * 512;
    unsigned short* lB0 = Bs + wave * 512;
    unsigned short* lB1 = Bs + 2048 + wave * 512;

    const floatx4 zero = {0.f, 0.f, 0.f, 0.f};
    floatx4 acc[4][4];
#pragma unroll
    for (int i = 0; i < 4; ++i)
#pragma unroll
        for (int j = 0; j < 4; ++j) acc[i][j] = zero;

    // fragment read swizzle: chunk = quad ^ ((l15>>1)&3)
    const int chO = ((quad ^ ((l15 >> 1) & 3)) << 3);   // shorts

    floatx4 u0l = zero, u0h = zero, u1l = zero, u1h = zero;
    floatx4 p0l = zero, p0h = zero, p1l = zero, p1h = zero;
    if (!AGL) {
        u0l = *(const floatx4*)(gA0f);     u0h = *(const floatx4*)(gA0f + 4);
        u1l = *(const floatx4*)(gA1f);     u1h = *(const floatx4*)(gA1f + 4);
    }

#define GSTEP(KT, UL0, UH0, UL1, UH1, PL0, PH0, PL1, PH1)                         \
    {                                                                              \
        __syncthreads();  /* prev LDS readers done */                              \
        gload16(gB0 + (KT) * 32, lB0);                                             \
        gload16(gB1 + (KT) * 32, lB1);                                             \
        if (AGL) {                                                                 \
            gload16(gA0u + (KT) * 32, lA0);                                        \
            gload16(gA1u + (KT) * 32, lA1);                                        \
        } else {                                                                   \
            *(bf16x8*)(As + tid * 8)        = cvt8(UL0, UH0);                      \
            *(bf16x8*)(As + 2048 + tid * 8) = cvt8(UL1, UH1);                      \
        }                                                                          \
        __syncthreads();  /* LDS tiles valid */                                    \
        if (!AGL && ((KT) + 1 < kIters)) {  /* prefetch overlaps MFMA */           \
            PL0 = *(const floatx4*)(gA0f + ((KT) + 1) * 32);                       \
            PH0 = *(const floatx4*)(gA0f + ((KT) + 1) * 32 + 4);                   \
            PL1 = *(const floatx4*)(gA1f + ((KT) + 1) * 32);                       \
            PH1 = *(const floatx4*)(gA1f + ((KT) + 1) * 32 + 4);                   \
        }                                                                          \
        bf16x8 af[4], bfr[4];                                                      \
        _Pragma("unroll")                                                          \
        for (int t = 0; t < 4; ++t) {                                              \
            af[t]  = *(const bf16x8*)(As + (wr * 64 + t * 16 + l15) * 32 + chO);   \
            bfr[t] = *(const bf16x8*)(Bs + (wc * 64 + t * 16 + l15) * 32 + chO);   \
        }                                                                          \
        _Pragma("unroll")                                                          \
        for (int tm = 0; tm < 4; ++tm)                                             \
            _Pragma("unroll")                                                      \
            for (int tn = 0; tn < 4; ++tn)                                         \
                acc[tm][tn] = __builtin_amdgcn_mfma_f32_16x16x32_bf16(             \
                    af[tm], bfr[tn], acc[tm][tn], 0, 0, 0);                        \
    }

    for (int kt = 0; kt < kIters; kt += 2) {
        GSTEP(kt,     u0l, u0h, u1l, u1h, p0l, p0h, p1l, p1h);
        GSTEP(kt + 1, p0l, p0h, p1l, p1h, u0l, u0h, u1l, u1h);
    }
#undef GSTEP

    // Epilogue. C/D layout: col = lane&15, row = quad*4 + reg.
#pragma unroll
    for (int tm = 0; tm < 4; ++tm) {
        const int rbase = row0 + wr * 64 + tm * 16 + quad * 4;
#pragma unroll
        for (int tn = 0; tn < 4; ++tn) {
            const int cc = col0 + wc * 64 + tn * 16 + l15;
#pragma unroll
            for (int rr = 0; rr < 4; ++rr) {
                float vv = acc[tm][tn][rr];
                const int rowg = rbase + rr;
                if (MODE == 0) {     // q_s/k_s[((n*12+h)*256+i)*1024 + r*64+d]
                    const int tg = nBase * HALF_TOK + rowg;   // global token
                    const int m = tg / 12, n = tg - m * 12;
                    const int r = m >> 8, i = m & 255;
                    const int sel = cc >= 768 ? 1 : 0;
                    const int ccl = cc - sel * 768;
                    const int h = ccl >> 6, d = ccl & 63;
                    ((unsigned short*)Cout)[(size_t)sel * QK_HALF
                        + ((size_t)(n * 12 + h) * 256 + i) * 1024 + r * 64 + d]
                        = f2bf(vv + bias[cc]);
                } else if (MODE == 2) {   // ctx_q[(((cc>>6)*256+i)*12+n)*768 + h*64+d]
                    ((unsigned short*)Cout)[((((size_t)(cc >> 6)) * 256 + rowg) * 12
                        + nIdx) * 768 + hIdx * 64 + (cc & 63)] = f2bf(vv);
                } else if (MODE == 3) {   // v^T: rowg = h*64+d, cc = r*256+j
                    const int h = rowg >> 6, d = rowg & 63;
                    const int r = cc >> 8, j = cc & 255;
                    ((unsigned short*)Cout)[VT_BASE + (size_t)(r >> 2) * VT_QUARTER
                        + ((size_t)(nIdx * 12 + h) * 256 + (r & 3) * 64 + d) * 256 + j]
                        = f2bf(vv + bias[rowg]);
                } else {                  // MODE 4: f32 out token-contiguous
                    ((float*)Cout)[((size_t)(nBase * 12288 + rowg)) * 768 + cc]
                        = vv + bias[cc];
                }
            }
        }
    }
}

// ---------------------------------------------------------------------------
// Fused scores + bias + softmax. Tile 128 rows x 256 cols (full softmax rows
// in-block). 512 threads = 8 waves; wave w owns rows [w*16,w*16+16), acc[16].
// Both operands AGL, K=1024. grid (1,2,144); z = n*12+h pair-block layout.
// ---------------------------------------------------------------------------
__global__ __launch_bounds__(512)
void scores_sm(const unsigned short* __restrict__ q,
               const unsigned short* __restrict__ k,
               const int* __restrict__ buckets,
               const float* __restrict__ rb,
               float* __restrict__ probs)
{
    __shared__ __align__(16) unsigned short As[128 * 32];   //  8 KB
    __shared__ __align__(16) unsigned short Bs[256 * 32];   // 16 KB

    const int tid  = threadIdx.x;
    const int w    = tid >> 6, lane = tid & 63;
    const int quad = lane >> 4, l15 = lane & 15;

    const int lin = (int)blockIdx.z * 2 + (int)blockIdx.y;
    const int tt  = (lin & 7) * 36 + (lin >> 3);
    const int by  = tt % 2, bz = tt / 2;
    const int row0 = by * 128;
    const int h = bz % 12, n = bz / 12;

    const int rA0 = tid >> 2;
    const int ck  = tid & 3;
    const int sw  = (tid >> 3) & 3;
    const int kko = ((ck ^ sw) << 3);

    const unsigned short* gA  = q + ((size_t)bz * 256 + row0 + rA0) * 1024 + kko;
    const unsigned short* gB0 = k + ((size_t)bz * 256 + rA0) * 1024 + kko;
    const unsigned short* gB1 = k + ((size_t)bz * 256 + rA0 + 128) * 1024 + kko;

    unsigned short* lA  = As + w * 512;
    unsigned short* lB0 = Bs + w * 512;
    unsigned short* lB1 = Bs + 4096 + w * 512;

    const floatx4 zero = {0.f, 0.f, 0.f, 0.f};
    floatx4 acc[16];
#pragma unroll
    for (int t = 0; t < 16; ++t) acc[t] = zero;

    const int chO = ((quad ^ ((l15 >> 1) & 3)) << 3);

    for (int kt = 0; kt < 32; ++kt) {
        __syncthreads();
        gload16(gA  + kt * 32, lA);
        gload16(gB0 + kt * 32, lB0);
        gload16(gB1 + kt * 32, lB1);
        __syncthreads();
        const bf16x8 af = *(const bf16x8*)(As + (w * 16 + l15) * 32 + chO);
#pragma unroll
        for (int tn = 0; tn < 16; ++tn) {
            const bf16x8 bfr = *(const bf16x8*)(Bs + (tn * 16 + l15) * 32 + chO);
            acc[tn] = __builtin_amdgcn_mfma_f32_16x16x32_bf16(af, bfr, acc[tn], 0, 0, 0);
        }
    }

    const int i0 = row0 + w * 16 + quad * 4;
    float mx[4] = {-3.4e38f, -3.4e38f, -3.4e38f, -3.4e38f};
#pragma unroll
    for (int tn = 0; tn < 16; ++tn) {
        const int j = tn * 16 + l15;
#pragma unroll
        for (int rr = 0; rr < 4; ++rr) {
            const int bkt = buckets[((size_t)h * 256 + i0 + rr) * 256 + j];
            const float s = acc[tn][rr] * 0.03125f + rb[bkt * 12 + n];
            acc[tn][rr] = s;
            mx[rr] = fmaxf(mx[rr], s);
        }
    }
#pragma unroll
    for (int rr = 0; rr < 4; ++rr)
#pragma unroll
        for (int off = 1; off < 16; off <<= 1)
            mx[rr] = fmaxf(mx[rr], __shfl_xor(mx[rr], off, 64));
    float sm[4] = {0.f, 0.f, 0.f, 0.f};
#pragma unroll
    for (int tn = 0; tn < 16; ++tn)
#pragma unroll
        for (int rr = 0; rr < 4; ++rr) {
            const float e = expf(acc[tn][rr] - mx[rr]);
            acc[tn][rr] = e;
            sm[rr] += e;
        }
#pragma unroll
    for (int rr = 0; rr < 4; ++rr)
#pragma unroll
        for (int off = 1; off < 16; off <<= 1)
            sm[rr] += __shfl_xor(sm[rr], off, 64);
    float inv[4];
#pragma unroll
    for (int rr = 0; rr < 4; ++rr) inv[rr] = 1.f / sm[rr];

    float* prow = probs + ((size_t)(h * 12 + n)) * 65536;
#pragma unroll
    for (int tn = 0; tn < 16; ++tn) {
        const int j = tn * 16 + l15;
#pragma unroll
        for (int rr = 0; rr < 4; ++rr)
            prow[(size_t)(i0 + rr) * 256 + j] = acc[tn][rr] * inv[rr];
    }
}

// ---------------------------------------------------------------------------
// f32 -> bf16 bulk convert, 8 elems/thread. n multiple of 2048.
// ---------------------------------------------------------------------------
__global__ __launch_bounds__(256)
void cvt_bulk(const float* __restrict__ src, unsigned short* __restrict__ dst, int n)
{
    const int i = (blockIdx.x * 256 + threadIdx.x) * 8;
    if (i >= n) return;
    floatx4 a = ((const floatx4*)(src + i))[0];
    floatx4 b = ((const floatx4*)(src + i))[1];
    *(bf16x8*)(dst + i) = cvt8(a, b);
}

// f32 x (token-major) -> bf16 x_n (n-major): x_n[(n*4096+m)*768+e].
// grid 18432 x 256 threads, 8 elems/thread, exact cover of 49152*768.
__global__ __launch_bounds__(256)
void cvt_xn(const float* __restrict__ src, unsigned short* __restrict__ dst)
{
    const size_t flat = ((size_t)blockIdx.x * 256 + threadIdx.x) * 8;
    const int tok = (int)(flat / 768);
    const int e   = (int)(flat - (size_t)tok * 768);
    const int n = tok % 12, m = tok / 12;
    floatx4 a = ((const floatx4*)(src + flat))[0];
    floatx4 b = ((const floatx4*)(src + flat))[1];
    *(bf16x8*)(dst + ((size_t)(n * 4096 + m)) * 768 + e) = cvt8(a, b);
}

// ---------------------------------------------------------------------------
// prep: buckets (blocks 0..3071) + weight cvt & bias concat (blocks 3072..).
// ---------------------------------------------------------------------------
__global__ __launch_bounds__(256)
void prep(const int* __restrict__ dist, int* __restrict__ buckets,
          const float* __restrict__ Wq, const float* __restrict__ Wk,
          const float* __restrict__ Wv, const float* __restrict__ Wo,
          const float* __restrict__ bq, const float* __restrict__ bk,
          unsigned short* __restrict__ wqk, unsigned short* __restrict__ wvb,
          unsigned short* __restrict__ wob, float* __restrict__ bqk)
{
    if (blockIdx.x < 3072) {
        const int idx = blockIdx.x * 256 + threadIdx.x;
        if (idx >= B_ * C_ * C_) return;
        const int dv = dist[idx];
        const int n = dv < 0 ? -dv : dv;
        int bkt;
        if (n < 16) {
            bkt = n;
        } else {
            const float lg = logf((float)n * 0.0625f);        // log(n/16)
            const float t  = (lg / 8.047189562170502f) * 15.0f;
            bkt = 16 + (int)t;
            if (bkt > 31) bkt = 31;
        }
        buckets[idx] = bkt;
        return;
    }
    const int gid = (blockIdx.x - 3072) * 256 + threadIdx.x;
    const int W8 = 73728;                     // 589824 / 8
    if (gid < 4 * W8) {
        const int sec = gid / W8, off = (gid - sec * W8) * 8;
        const float* src = (sec == 0) ? Wq : (sec == 1) ? Wk : (sec == 2) ? Wv : Wo;
        unsigned short* dst = (sec == 0) ? wqk : (sec == 1) ? (wqk + 589824)
                              : (sec == 2) ? wvb : wob;
        floatx4 a = ((const floatx4*)(src + off))[0];
        floatx4 b = ((const floatx4*)(src + off))[1];
        *(bf16x8*)(dst + off) = cvt8(a, b);
    } else {
        const int b = gid - 4 * W8;
        if (b < 1536) bqk[b] = (b < 768) ? bq[b] : bk[b - 768];
    }
}

// ---------------------------------------------------------------------------
// Memory plan.
// d_out (188,743,680 B):
//   [0 : 150,994,944)  -- phase 1/2: q_s [0:75.5M), k_s [75.5M:151M)  (bf16)
//                      -- phase 3:   x_n bf16 (n-major) [0:75.5M), dead after
//                                    V-proj; O0/O1 overwrite it.
//                                    vt_all [75.5M:151M) quarter-major
//                                    (q = r>>2 at VT_BASE + q*VT_QUARTER);
//                                    O2 overwrites q0/q1, O3 overwrites q2/q3
//                                    (each consumed by PV_q before).
//                      -- final:     out f32 rows token-contiguous.
//   probs f32 [150,994,944 : 188,743,680) -- x_bf halves pre-scores; then
//                                    scores_sm writes final probs (live to end).
// d_ws (28,311,552 B) -- ALL DISJOINT, no lifetime reuse:
//   wo_bf   @ 0           (1,179,648)
//   wv_bf   @ 1,179,648   (1,179,648)
//   bqk f32 @ 2,359,296   (6,144)
//   ctx_q   @ 2,365,440   (18,874,368)   [PV_q writes, O_q reads, ping-pong]
//   buckets @ 21,239,808  (3,145,728)
//   wqk_bf  @ 24,385,536  (2,359,296)    -> ends 26,744,832 <= ws_size
// Phase 3: cvt_xn x -> x_n; V-proj^T (A=Wv, B=x_n, coalesced vt writes);
//          for q=0..3: PV_q -> ctx_q (ws); O_q -> out[q*37.7M:(q+1)*37.7M).
// ---------------------------------------------------------------------------
extern "C" void kernel_launch(void* const* d_in, const int* in_sizes, int n_in,
                              void* d_out, int out_size, void* d_ws, size_t ws_size,
                              hipStream_t stream)
{
    const float* x    = (const float*)d_in[0];
    const int*   dist = (const int*)d_in[1];
    const float* Wq   = (const float*)d_in[2];
    const float* bq   = (const float*)d_in[3];
    const float* Wk   = (const float*)d_in[4];
    const float* bk   = (const float*)d_in[5];
    const float* Wv   = (const float*)d_in[6];
    const float* bv   = (const float*)d_in[7];
    const float* Wo   = (const float*)d_in[8];
    const float* bo   = (const float*)d_in[9];
    const float* rb   = (const float*)d_in[10];

    float* outp  = (float*)d_out;
    float* probs = (float*)d_out + (size_t)TOK * E_;      // f32 elem 37,748,736

    unsigned short* dob  = (unsigned short*)d_out;        // bf16 view of out
    unsigned short* qs   = dob;                           // [n][h][i][rd]
    unsigned short* ks   = dob + QK_HALF;
    unsigned short* x_bf = (unsigned short*)probs;        // x half, pre-scores

    char* ws = (char*)d_ws;
    unsigned short* wo_bf  = (unsigned short*)(ws);
    unsigned short* wv_bf  = (unsigned short*)(ws + 1179648);
    float*          bqk    = (float*)(ws + 2359296);
    unsigned short* ctx_q  = (unsigned short*)(ws + 2365440);
    int*            buckets= (int*)(ws + 21239808);
    unsigned short* wqk_bf = (unsigned short*)(ws + 24385536);

    dim3 blk(256);

    prep<<<dim3(4230), blk, 0, stream>>>(dist, buckets, Wq, Wk, Wv, Wo, bq, bk,
                                         wqk_bf, wv_bf, wo_bf, bqk);

    // Phase 1: per-half {cvt x -> bf16 in probs region, fused q+k proj (AGL)}
    for (int half = 0; half < 2; ++half) {
        cvt_bulk<<<dim3(9216), blk, 0, stream>>>(
            x + (size_t)half * HALF_TOK * 768, x_bf, HALF_TOK * 768);
        gemm_bt<0><<<dim3(12, 192), blk, 0, stream>>>(x_bf, wqk_bf, bqk, qs, half);
    }

    // Phase 2: fused scores + bias + softmax (writes final probs f32)
    scores_sm<<<dim3(1, 2, 144), dim3(512), 0, stream>>>(qs, ks, buckets, rb, probs);

    // Phase 3: cvt x -> x_n (n-major) @ out[0:75.5M); transposed V-proj ->
    //          vt (coalesced); 4x (PV quarter -> ctx_q, O quarter -> out).
    cvt_xn<<<dim3(18432), blk, 0, stream>>>(x, dob);
    gemm_bt<3><<<dim3(32, 6, 12), blk, 0, stream>>>(wv_bf, dob, bv, dob, 0);
    for (int q = 0; q < 4; ++q) {
        gemm_bt<2><<<dim3(2, 2, 144), blk, 0, stream>>>(probs, dob, nullptr, ctx_q, q);
        gemm_bt<4><<<dim3(6, 96), blk, 0, stream>>>(ctx_q, wo_bf, bo, outp, q);
    }
}